// Round 23
// baseline (46.942 us; speedup 1.0000x reference)
//
#include <hip/hip_runtime.h>
#include <cmath>

#define Hn 512
#define Wn 512
#define Bn 32
#define BANDS 16
#define BH 32                       // output rows per band
#define NBLK (Bn * BANDS)           // 512 blocks
#define NT 512                      // 1 thread per column

struct GaussW { float g[9]; };

__device__ __forceinline__ void load_row(
    const float* __restrict__ pir, const float* __restrict__ pvi,
    const float* __restrict__ pfu, int y, int x,
    float& a, float& v, float& f)
{
    bool ok = (unsigned)y < (unsigned)Hn;
    size_t o = ok ? ((size_t)y * Wn + x) : 0;
    float aa = pir[o], vv = pvi[o], ff = pfu[o];
    a = ok ? aa : 0.f;  v = ok ? vv : 0.f;  f = ok ? ff : 0.f;
}

__device__ __forceinline__ void stage_row(
    float4* rowq, int x, float a, float v, float f)
{
    float di = a - f, dv = v - f;
    rowq[x + 4] = make_float4(a, v, di * di, dv * dv);
}

// one image row: horizontal 9-tap from LDS + in-register vertical update.
// j, emit compile-time after full unroll (rule #20). pd computed at tap.
__device__ __forceinline__ void compute_row(
    const float4* rowq, int x, int j, bool emit,
    float mk, const GaussW& gw,
    float* hb_i, float* hb_v, float* ag_i, float* ag_v, float* ag_q,
    float& Sbi, float& Sbv, float& acc)
{
    float bi = 0.f, bv = 0.f, ga = 0.f, gv = 0.f, qd = 0.f;
    #pragma unroll
    for (int i = 0; i < 9; ++i) {
        float4 q = rowq[x + i];
        float gg = gw.g[i];
        bi += q.z;  bv += q.w;
        ga = fmaf(gg, q.x, ga);
        gv = fmaf(gg, q.y, gv);
        qd = fmaf(gg, (q.x - q.y) * (q.x + q.y), qd);   // pd = a^2 - v^2
    }
    Sbi += bi - hb_i[j];  hb_i[j] = bi;
    Sbv += bv - hb_v[j];  hb_v[j] = bv;
    float mi = 0.f, mv = 0.f, mq = 0.f;
    const float g8 = gw.g[8];
    #pragma unroll
    for (int s = 0; s < 9; ++s) {
        if (s == j) {
            mi = fmaf(g8, ga, ag_i[j]);
            mv = fmaf(g8, gv, ag_v[j]);
            mq = fmaf(g8, qd, ag_q[j]);
        } else {
            float w = gw.g[(j - s - 1 + 9) % 9];
            ag_i[s] = fmaf(w, ga, ag_i[s]);
            ag_v[s] = fmaf(w, gv, ag_v[s]);
            ag_q[s] = fmaf(w, qd, ag_q[s]);
        }
    }
    ag_i[j] = 0.f; ag_v[j] = 0.f; ag_q[j] = 0.f;
    if (emit) {
        float dvar = mq - (mi - mv) * (mi + mv);   // var_i - var_v
        float m1  = (dvar > 0.f) ? 1.f : 0.f;
        float sel = (m1 + mk > 0.f) ? 1.f : 0.f;
        acc += sel * (Sbi * (1.f / 81.f)) + (1.f - sel) * (Sbv * (1.f / 81.f));
    }
}

// R23 = R22 with the phase REORDERED: {issue loads -> compute -> wait+stage
// -> barrier}. R22's order was {stage -> issue loads -> compute -> barrier}:
// hipcc emits s_waitcnt vmcnt(0) before every s_barrier (m97-verified), so
// the barrier DRAINED the just-issued prefetch -- every phase paid full
// memory latency (measured ~6200 cyc/phase vs ~1600 of work). Consuming the
// loads before the barrier makes the drain free; compute covers the latency.
__global__ __launch_bounds__(NT) void fuse_loss_kernel(
    const float* __restrict__ vis, const float* __restrict__ ir,
    const float* __restrict__ fus, const float* __restrict__ mask,
    float* __restrict__ ws, GaussW gw)
{
    __shared__ __align__(16) float4 s_q[2][2][Wn + 8];   // (a,v,d2i,d2v) 33280 B
    __shared__ float  s_part[8];

    const int t    = threadIdx.x;                 // column x
    const int img  = blockIdx.x >> 4;
    const int band = blockIdx.x & 15;
    const int Y0   = band * BH;
    const size_t ibase = (size_t)img * (size_t)(Hn * Wn);
    const float* pir = ir  + ibase;
    const float* pvi = vis + ibase;
    const float* pfu = fus + ibase;
    const float* pmk = mask + ibase;

    // zero the 4-px horizontal halos once (stage never touches them)
    if (t < 32) {
        int b = (t >> 4) & 1, rr = (t >> 3) & 1, e = t & 7;
        int col = (e < 4) ? e : (Wn + e);         // 0..3, 516..519
        s_q[b][rr][col] = make_float4(0.f, 0.f, 0.f, 0.f);
    }

    // vertical state (all statically indexed after unroll)
    float hb_i[9], hb_v[9], ag_i[9], ag_v[9], ag_q[9];
    #pragma unroll
    for (int s = 0; s < 9; ++s) {
        hb_i[s] = 0.f; hb_v[s] = 0.f;
        ag_i[s] = 0.f; ag_v[s] = 0.f; ag_q[s] = 0.f;
    }
    float Sbi = 0.f, Sbv = 0.f, acc = 0.f;

    // prologue: rows r=0,1 (y=Y0-4,Y0-3) -> buf0
    float aA, vA, fA, aB, vB, fB;
    load_row(pir, pvi, pfu, Y0 - 4, t, aA, vA, fA);
    load_row(pir, pvi, pfu, Y0 - 3, t, aB, vB, fB);
    stage_row(s_q[0][0], t, aA, vA, fA);
    stage_row(s_q[0][1], t, aB, vB, fB);
    float mkA = 0.f, mkB = 0.f;
    __syncthreads();

    #pragma unroll
    for (int p = 0; p < 20; ++p) {
        const int cur = p & 1;
        // issue loads for rows 2p+2, 2p+3 (consumed by stage THIS phase,
        // after compute has covered the latency)
        if (p < 19) {
            load_row(pir, pvi, pfu, Y0 + 2 * p - 2, t, aA, vA, fA);
            load_row(pir, pvi, pfu, Y0 + 2 * p - 1, t, aB, vB, fB);
        }
        // issue mask loads for phase p+1's emit rows (consumed after next
        // barrier; issued early so the drain at THIS barrier is already met)
        if (p >= 3 && p < 19) {
            mkA = pmk[(size_t)(Y0 + 2 * p - 6) * Wn + t];
            mkB = pmk[(size_t)(Y0 + 2 * p - 5) * Wn + t];
        }
        // compute rows r=2p, 2p+1 from buf[cur]; emit when r>=8
        compute_row(s_q[cur][0], t, (2 * p) % 9,     (p >= 4),
                    (p >= 4) ? mkA : 0.f, gw,
                    hb_i, hb_v, ag_i, ag_v, ag_q, Sbi, Sbv, acc);
        compute_row(s_q[cur][1], t, (2 * p + 1) % 9, (p >= 4),
                    (p >= 4) ? mkB : 0.f, gw,
                    hb_i, hb_v, ag_i, ag_v, ag_q, Sbi, Sbv, acc);
        // stage rows 2p+2, 2p+3 into the other buffer (waits the loads;
        // they are DONE or nearly so -> barrier drain is then free)
        if (p < 19) {
            stage_row(s_q[cur ^ 1][0], t, aA, vA, fA);
            stage_row(s_q[cur ^ 1][1], t, aB, vB, fB);
        }
        __syncthreads();
    }

    // block reduction -> one partial per block
    #pragma unroll
    for (int off = 32; off > 0; off >>= 1)
        acc += __shfl_down(acc, off, 64);
    if ((t & 63) == 0) s_part[t >> 6] = acc;
    __syncthreads();
    if (t == 0) {
        float s = 0.f;
        #pragma unroll
        for (int i = 0; i < 8; ++i) s += s_part[i];
        ws[blockIdx.x] = s;
    }
}

__global__ __launch_bounds__(256) void reduce_kernel(const float* __restrict__ ws,
                                                     float* __restrict__ out)
{
    __shared__ float sp[4];
    int t = threadIdx.x;
    float v = 0.f;
    for (int i = t; i < NBLK; i += 256) v += ws[i];
    #pragma unroll
    for (int off = 32; off > 0; off >>= 1)
        v += __shfl_down(v, off, 64);
    if ((t & 63) == 0) sp[t >> 6] = v;
    __syncthreads();
    if (t == 0)
        out[0] = (sp[0] + sp[1] + sp[2] + sp[3]) * (1.f / ((float)Bn * Hn * Wn));
}

extern "C" void kernel_launch(void* const* d_in, const int* in_sizes, int n_in,
                              void* d_out, int out_size, void* d_ws, size_t ws_size,
                              hipStream_t stream) {
    const float* vis  = (const float*)d_in[0];
    const float* ir   = (const float*)d_in[1];
    const float* fus  = (const float*)d_in[2];
    const float* mask = (const float*)d_in[3];
    float* out = (float*)d_out;
    float* ws  = (float*)d_ws;

    GaussW gw;
    double g[9], s = 0.0;
    for (int i = 0; i < 9; ++i) {
        int x = i - 4;
        g[i] = exp(-(double)(x * x) / 4.5);
        s += g[i];
    }
    for (int i = 0; i < 9; ++i) gw.g[i] = (float)(g[i] / s);

    fuse_loss_kernel<<<NBLK, NT, 0, stream>>>(vis, ir, fus, mask, ws, gw);
    reduce_kernel<<<1, 256, 0, stream>>>(ws, out);
}